// Round 1
// baseline (903.623 us; speedup 1.0000x reference)
//
#include <hip/hip_runtime.h>
#include <cmath>

// Shapes: B=8, N=4096, D=128, R=512, K=64
// d_in: 0 Ahat[8,4096,4096] 1 node_embs[8,4096,128] 2 mask(unused) 3 ht[8,512]
//       4 prev_Q[8,128,128] 5 W_map[512,128] 6 b_map[128]
//       7 Wu 8 Uu 9 bu 10 Wr 11 Ur 12 br 13 Wh 14 Uh 15 bh 16 static_W (all [128,128])
// d_out (fp32, 66576): out[8,64,128] @0, policy[8] @65536, scorer[8,128] @65544, entropy[8] @66568

__device__ __forceinline__ float sigmoidf_(float x){ return 1.0f/(1.0f+expf(-x)); }

// ---------------- K1: scorer = tanh(ht @ W_map + b_map), inv_norm ----------------
__global__ __launch_bounds__(128) void k_scorer(const float* __restrict__ ht,
    const float* __restrict__ W_map, const float* __restrict__ b_map,
    float* __restrict__ scorer_ws, float* __restrict__ inv_norm,
    float* __restrict__ scorer_out) {
  int b = blockIdx.x, d = threadIdx.x;
  __shared__ float htl[512];
  __shared__ float red[2];
  for (int e = d; e < 512; e += 128) htl[e] = ht[b*512 + e];
  __syncthreads();
  float acc = b_map[d];
  #pragma unroll 8
  for (int r = 0; r < 512; ++r) acc += htl[r] * W_map[r*128 + d];
  float sc = tanhf(acc);
  scorer_ws[b*128 + d] = sc;
  scorer_out[b*128 + d] = sc;
  float ss = sc*sc;
  #pragma unroll
  for (int off = 32; off; off >>= 1) ss += __shfl_xor(ss, off);
  if ((d & 63) == 0) red[d >> 6] = ss;
  __syncthreads();
  if (d == 0) inv_norm[b] = 1.0f / sqrtf(red[0] + red[1]);
}

// ---------------- K2: scores[b,n] = dot(node_embs[b,n,:], scorer[b,:]) * inv_norm[b] ----------------
__global__ __launch_bounds__(256) void k_scores(const float* __restrict__ node_embs,
    const float* __restrict__ scorer_ws, const float* __restrict__ inv_norm,
    float* __restrict__ scores) {
  int blk = blockIdx.x;           // 128 blocks
  int b = blk >> 4;
  int n = ((blk & 15) << 8) + threadIdx.x;
  __shared__ float sc[128];
  if (threadIdx.x < 128) sc[threadIdx.x] = scorer_ws[b*128 + threadIdx.x];
  __syncthreads();
  const float4* row = (const float4*)(node_embs + ((size_t)(b*4096 + n)) * 128);
  float acc = 0.f;
  #pragma unroll
  for (int j = 0; j < 32; ++j) {
    float4 v = row[j];
    acc += v.x*sc[4*j] + v.y*sc[4*j+1] + v.z*sc[4*j+2] + v.w*sc[4*j+3];
  }
  scores[b*4096 + n] = acc * inv_norm[b];
}

// ---------------- K3: softmax stats + entropy + top-64 + tanh(vals) + policy ----------------
__global__ __launch_bounds__(256) void k_topk(const float* __restrict__ scores,
    float* __restrict__ outPolicy, float* __restrict__ outEntropy,
    int* __restrict__ topk_idx, float* __restrict__ tanhs) {
  int b = blockIdx.x, t = threadIdx.x;
  int wave = t >> 6, lane = t & 63;
  const float* s = scores + b*4096;
  float v[16];
  #pragma unroll
  for (int j = 0; j < 16; ++j) v[j] = s[j*256 + t];   // index = j*256 + t

  __shared__ float redf[8];
  __shared__ int   redi[4];

  // global max
  float m = v[0];
  #pragma unroll
  for (int j = 1; j < 16; ++j) m = fmaxf(m, v[j]);
  #pragma unroll
  for (int off = 32; off; off >>= 1) m = fmaxf(m, __shfl_xor(m, off));
  if (lane == 0) redf[wave] = m;
  __syncthreads();
  m = fmaxf(fmaxf(redf[0], redf[1]), fmaxf(redf[2], redf[3]));
  __syncthreads();

  // sum exp, sum e*(s-m)
  float S = 0.f, E1 = 0.f;
  #pragma unroll
  for (int j = 0; j < 16; ++j) { float e = expf(v[j] - m); S += e; E1 += e*(v[j]-m); }
  #pragma unroll
  for (int off = 32; off; off >>= 1) { S += __shfl_xor(S, off); E1 += __shfl_xor(E1, off); }
  if (lane == 0) { redf[wave] = S; redf[4 + wave] = E1; }
  __syncthreads();
  S  = redf[0] + redf[1] + redf[2] + redf[3];
  E1 = redf[4] + redf[5] + redf[6] + redf[7];
  float logS = logf(S);
  if (t == 0) outEntropy[b] = logS - E1 / S;

  // iterative top-64 (matches jax: descending, smallest index on ties)
  float vsum = 0.f;
  for (int k = 0; k < 64; ++k) {
    float bv = v[0]; int bi = t;
    #pragma unroll
    for (int j = 1; j < 16; ++j) { float x = v[j]; if (x > bv) { bv = x; bi = j*256 + t; } }
    #pragma unroll
    for (int off = 32; off; off >>= 1) {
      float ov = __shfl_xor(bv, off); int oi = __shfl_xor(bi, off);
      if (ov > bv || (ov == bv && oi < bi)) { bv = ov; bi = oi; }
    }
    __syncthreads();
    if (lane == 0) { redf[wave] = bv; redi[wave] = bi; }
    __syncthreads();
    float wv = redf[0]; int wi = redi[0];
    #pragma unroll
    for (int w2 = 1; w2 < 4; ++w2) {
      float ov = redf[w2]; int oi = redi[w2];
      if (ov > wv || (ov == wv && oi < wi)) { wv = ov; wi = oi; }
    }
    if (t == 0) { topk_idx[b*64 + k] = wi; tanhs[b*64 + k] = tanhf(wv); vsum += wv; }
    if ((wi & 255) == t) v[wi >> 8] = -INFINITY;
  }
  if (t == 0) outPolicy[b] = vsum * (1.0f/64.0f) - m - logS;
}

// ---------------- K4: gather G[b,k,:] = node_embs[b, topk[k], :] ----------------
__global__ __launch_bounds__(256) void k_gather(const float* __restrict__ node_embs,
    const int* __restrict__ topk_idx, float* __restrict__ G) {
  int b = blockIdx.x, t = threadIdx.x;
  __shared__ int idx[64];
  if (t < 64) idx[t] = topk_idx[b*64 + t];
  __syncthreads();
  for (int e = t; e < 8192; e += 256) {
    int k = e >> 7, d = e & 127;
    G[(size_t)b*8192 + e] = node_embs[((size_t)(b*4096 + idx[k]))*128 + d];
  }
}

// ---------------- K5a: update & reset gates ----------------
__global__ __launch_bounds__(128) void k_gru1(const float* __restrict__ G,
    const float* __restrict__ tanhs, const float* __restrict__ prevQ,
    const float* __restrict__ Wu, const float* __restrict__ Uu, const float* __restrict__ bu,
    const float* __restrict__ Wr, const float* __restrict__ Ur, const float* __restrict__ br,
    float* __restrict__ u_out, float* __restrict__ r_out) {
  int b = blockIdx.x >> 5, i0 = (blockIdx.x & 31) * 4, k = threadIdx.x;
  __shared__ float Gl[64*129];
  __shared__ float Wl[4][128], Ul[4][128], Wrl[4][128], Url[4][128];
  for (int e = k; e < 8192; e += 128) { int rr = e >> 7; Gl[rr*129 + (e & 127)] = G[(size_t)b*8192 + e]; }
  #pragma unroll
  for (int ii = 0; ii < 4; ++ii) {
    Wl[ii][k]  = Wu[(i0+ii)*128 + k]; Ul[ii][k]  = Uu[(i0+ii)*128 + k];
    Wrl[ii][k] = Wr[(i0+ii)*128 + k]; Url[ii][k] = Ur[(i0+ii)*128 + k];
  }
  __syncthreads();
  int km = k & 63;
  float tk = tanhs[b*64 + km];
  const float* Gr = Gl + km*129;
  const float* Q = prevQ + (size_t)b*16384;
  float aW[4] = {0,0,0,0}, aU[4] = {0,0,0,0}, aWr[4] = {0,0,0,0}, aUr[4] = {0,0,0,0};
  for (int j = 0; j < 128; ++j) {
    float g = Gr[j], q = Q[j*128 + k];
    #pragma unroll
    for (int ii = 0; ii < 4; ++ii) {
      aW[ii]  += Wl[ii][j]  * g;  aU[ii]  += Ul[ii][j]  * q;
      aWr[ii] += Wrl[ii][j] * g;  aUr[ii] += Url[ii][j] * q;
    }
  }
  #pragma unroll
  for (int ii = 0; ii < 4; ++ii) {
    int i = i0 + ii; size_t o = ((size_t)b*128 + i)*128 + k;
    u_out[o] = sigmoidf_(aW[ii]*tk  + aU[ii]  + bu[i*128 + k]);
    r_out[o] = sigmoidf_(aWr[ii]*tk + aUr[ii] + br[i*128 + k]);
  }
}

// ---------------- K5b: h_cap + new_Q ----------------
__global__ __launch_bounds__(128) void k_gru2(const float* __restrict__ G,
    const float* __restrict__ tanhs, const float* __restrict__ prevQ,
    const float* __restrict__ Wh, const float* __restrict__ Uh, const float* __restrict__ bh,
    const float* __restrict__ u_ws, const float* __restrict__ r_ws,
    float* __restrict__ Qn) {
  int b = blockIdx.x >> 5, i0 = (blockIdx.x & 31) * 4, k = threadIdx.x;
  __shared__ float Gl[64*129];
  __shared__ float Wl[4][128], Ul[4][128];
  for (int e = k; e < 8192; e += 128) { int rr = e >> 7; Gl[rr*129 + (e & 127)] = G[(size_t)b*8192 + e]; }
  #pragma unroll
  for (int ii = 0; ii < 4; ++ii) {
    Wl[ii][k] = Wh[(i0+ii)*128 + k]; Ul[ii][k] = Uh[(i0+ii)*128 + k];
  }
  __syncthreads();
  int km = k & 63;
  float tk = tanhs[b*64 + km];
  const float* Gr = Gl + km*129;
  const float* Q = prevQ + (size_t)b*16384;
  const float* Rw = r_ws + (size_t)b*16384;
  float aW[4] = {0,0,0,0}, aU[4] = {0,0,0,0};
  for (int j = 0; j < 128; ++j) {
    float g = Gr[j];
    float rq = Rw[j*128 + k] * Q[j*128 + k];
    #pragma unroll
    for (int ii = 0; ii < 4; ++ii) { aW[ii] += Wl[ii][j]*g; aU[ii] += Ul[ii][j]*rq; }
  }
  #pragma unroll
  for (int ii = 0; ii < 4; ++ii) {
    int i = i0 + ii; size_t o = ((size_t)b*128 + i)*128 + k;
    float hc = tanhf(aW[ii]*tk + aU[ii] + bh[i*128 + k]);
    float uu = u_ws[o];
    float qq = Q[i*128 + k];
    Qn[o] = (1.f - uu)*qq + uu*hc;
  }
}

// ---------------- K6: pooled adjacency gather + sym-normalize ----------------
__global__ __launch_bounds__(256) void k_poolA(const float* __restrict__ Ahat,
    const int* __restrict__ topk_idx, float* __restrict__ A_ws) {
  int b = blockIdx.x, t = threadIdx.x;
  __shared__ int idx[64];
  __shared__ float Al[64*65];
  __shared__ float di[64];
  if (t < 64) idx[t] = topk_idx[b*64 + t];
  __syncthreads();
  const float* Ab = Ahat + (size_t)b * 4096 * 4096;
  for (int e = t; e < 4096; e += 256) {
    int p = e >> 6, q = e & 63;
    Al[p*65 + q] = Ab[(size_t)idx[p]*4096 + idx[q]];
  }
  __syncthreads();
  if (t < 64) {
    float s = 0.f;
    for (int p = 0; p < 64; ++p) s += Al[p*65 + t];
    di[t] = 1.0f / sqrtf(s);
  }
  __syncthreads();
  for (int e = t; e < 4096; e += 256) {
    int p = e >> 6, q = e & 63;
    A_ws[(size_t)b*4096 + e] = di[p] * di[q] * Al[p*65 + q];
  }
}

// ---------------- K7: H0 = G@Qnew; h1 = relu(A@H0); M = h1@Ws; out = (h1 + relu(A@M))/2 ----------------
__global__ __launch_bounds__(512) void k_final(const float* __restrict__ G,
    const float* __restrict__ A_ws, const float* __restrict__ Qn,
    const float* __restrict__ Ws, float* __restrict__ out) {
  int b = blockIdx.x, t = threadIdx.x;
  int pg = t >> 7, d = t & 127;
  __shared__ float Al[64*64];
  __shared__ float buf[64*128];     // H0, then M
  const float* Gb = G  + (size_t)b*8192;
  const float* Q  = Qn + (size_t)b*16384;
  float* ob = out + (size_t)b*8192; // also used as h1 scratch (rewritten at end)
  for (int e = t; e < 4096; e += 512) Al[e] = A_ws[(size_t)b*4096 + e];
  __syncthreads();

  float acc[16];
  #pragma unroll
  for (int ii = 0; ii < 16; ++ii) acc[ii] = 0.f;
  for (int j = 0; j < 128; ++j) {
    float q = Q[j*128 + d];
    #pragma unroll
    for (int ii = 0; ii < 16; ++ii) acc[ii] += Gb[(pg + ii*4)*128 + j] * q;
  }
  #pragma unroll
  for (int ii = 0; ii < 16; ++ii) buf[(pg + ii*4)*128 + d] = acc[ii];
  __syncthreads();

  float hv[16];
  #pragma unroll
  for (int ii = 0; ii < 16; ++ii) acc[ii] = 0.f;
  for (int q2 = 0; q2 < 64; ++q2) {
    float h0 = buf[q2*128 + d];
    #pragma unroll
    for (int ii = 0; ii < 16; ++ii) acc[ii] += Al[(pg + ii*4)*64 + q2] * h0;
  }
  #pragma unroll
  for (int ii = 0; ii < 16; ++ii) { hv[ii] = fmaxf(acc[ii], 0.f); ob[(pg + ii*4)*128 + d] = hv[ii]; }
  __syncthreads();

  #pragma unroll
  for (int ii = 0; ii < 16; ++ii) acc[ii] = 0.f;
  for (int j = 0; j < 128; ++j) {
    float w = Ws[j*128 + d];
    #pragma unroll
    for (int ii = 0; ii < 16; ++ii) acc[ii] += ob[(pg + ii*4)*128 + j] * w;
  }
  #pragma unroll
  for (int ii = 0; ii < 16; ++ii) buf[(pg + ii*4)*128 + d] = acc[ii];
  __syncthreads();

  #pragma unroll
  for (int ii = 0; ii < 16; ++ii) acc[ii] = 0.f;
  for (int q2 = 0; q2 < 64; ++q2) {
    float mv = buf[q2*128 + d];
    #pragma unroll
    for (int ii = 0; ii < 16; ++ii) acc[ii] += Al[(pg + ii*4)*64 + q2] * mv;
  }
  #pragma unroll
  for (int ii = 0; ii < 16; ++ii)
    ob[(pg + ii*4)*128 + d] = 0.5f * (hv[ii] + fmaxf(acc[ii], 0.f));
}

extern "C" void kernel_launch(void* const* d_in, const int* in_sizes, int n_in,
                              void* d_out, int out_size, void* d_ws, size_t ws_size,
                              hipStream_t stream) {
  const float* Ahat      = (const float*)d_in[0];
  const float* node_embs = (const float*)d_in[1];
  const float* ht        = (const float*)d_in[3];
  const float* prev_Q    = (const float*)d_in[4];
  const float* W_map     = (const float*)d_in[5];
  const float* b_map     = (const float*)d_in[6];
  const float* Wu = (const float*)d_in[7];
  const float* Uu = (const float*)d_in[8];
  const float* bu = (const float*)d_in[9];
  const float* Wr = (const float*)d_in[10];
  const float* Ur = (const float*)d_in[11];
  const float* br = (const float*)d_in[12];
  const float* Wh = (const float*)d_in[13];
  const float* Uh = (const float*)d_in[14];
  const float* bh = (const float*)d_in[15];
  const float* staticW = (const float*)d_in[16];

  float* out = (float*)d_out;
  float* ws  = (float*)d_ws;
  // ws layout (floats), total 526,344 (~2.1 MB)
  float* scorer_ws = ws;              // 1024
  float* inv_norm  = ws + 1024;       // 8
  float* scores    = ws + 1032;       // 32768
  int*   topk_idx  = (int*)(ws + 33800); // 512
  float* tanhs     = ws + 34312;      // 512
  float* G         = ws + 34824;      // 65536
  float* u_ws      = ws + 100360;     // 131072
  float* r_ws      = ws + 231432;     // 131072
  float* Qn        = ws + 362504;     // 131072
  float* A_ws      = ws + 493576;     // 32768

  float* policy  = out + 65536;
  float* scr_out = out + 65544;
  float* entropy = out + 66568;

  k_scorer<<<8, 128, 0, stream>>>(ht, W_map, b_map, scorer_ws, inv_norm, scr_out);
  k_scores<<<128, 256, 0, stream>>>(node_embs, scorer_ws, inv_norm, scores);
  k_topk  <<<8, 256, 0, stream>>>(scores, policy, entropy, topk_idx, tanhs);
  k_gather<<<8, 256, 0, stream>>>(node_embs, topk_idx, G);
  k_gru1  <<<256, 128, 0, stream>>>(G, tanhs, prev_Q, Wu, Uu, bu, Wr, Ur, br, u_ws, r_ws);
  k_gru2  <<<256, 128, 0, stream>>>(G, tanhs, prev_Q, Wh, Uh, bh, u_ws, r_ws, Qn);
  k_poolA <<<8, 256, 0, stream>>>(Ahat, topk_idx, A_ws);
  k_final <<<8, 512, 0, stream>>>(G, A_ws, Qn, staticW, out);
}

// Round 2
// 859.051 us; speedup vs baseline: 1.0519x; 1.0519x over previous
//
#include <hip/hip_runtime.h>
#include <cmath>

// Shapes: B=8, N=4096, D=128, R=512, K=64
// d_in: 0 Ahat[8,4096,4096] 1 node_embs[8,4096,128] 2 mask(unused) 3 ht[8,512]
//       4 prev_Q[8,128,128] 5 W_map[512,128] 6 b_map[128]
//       7 Wu 8 Uu 9 bu 10 Wr 11 Ur 12 br 13 Wh 14 Uh 15 bh 16 static_W (all [128,128])
// d_out (fp32, 66576): out[8,64,128] @0, policy[8] @65536, scorer[8,128] @65544, entropy[8] @66568

__device__ __forceinline__ float sigmoidf_(float x){ return 1.0f/(1.0f+expf(-x)); }

// ---------- K1: scorer (recomputed per block) + scores ----------
// grid = 128 (16 blocks per batch), 256 threads
__global__ __launch_bounds__(256) void k_scores(const float* __restrict__ node_embs,
    const float* __restrict__ ht, const float* __restrict__ W_map,
    const float* __restrict__ b_map, float* __restrict__ scores,
    float* __restrict__ scorer_out) {
  int blk = blockIdx.x, t = threadIdx.x;
  int b = blk >> 4, part = blk & 15;
  __shared__ float htl[512];
  __shared__ float scn[128];
  __shared__ float red[2];
  for (int e = t; e < 512; e += 256) htl[e] = ht[b*512 + e];
  __syncthreads();
  float scv = 0.f;
  if (t < 128) {
    float acc = b_map[t];
    #pragma unroll 8
    for (int r = 0; r < 512; ++r) acc += htl[r] * W_map[r*128 + t];
    scv = tanhf(acc);
    float ss = scv*scv;
    #pragma unroll
    for (int off = 32; off; off >>= 1) ss += __shfl_xor(ss, off);
    if ((t & 63) == 0) red[t >> 6] = ss;
  }
  __syncthreads();
  float inv = 1.0f / sqrtf(red[0] + red[1]);
  if (t < 128) {
    scn[t] = scv * inv;
    if (part == 0) scorer_out[b*128 + t] = scv;
  }
  __syncthreads();
  int n = part*256 + t;
  const float4* row = (const float4*)(node_embs + ((size_t)(b*4096 + n)) * 128);
  float acc = 0.f;
  #pragma unroll
  for (int j = 0; j < 32; ++j) {
    float4 v = row[j];
    acc += v.x*scn[4*j] + v.y*scn[4*j+1] + v.z*scn[4*j+2] + v.w*scn[4*j+3];
  }
  scores[b*4096 + n] = acc;
}

// ---------- K2: softmax stats + top-64 (binary-search select) + gather G + pool A ----------
// grid = 8 (one per batch), 256 threads
__global__ __launch_bounds__(256) void k_select(const float* __restrict__ scores,
    const float* __restrict__ node_embs, const float* __restrict__ Ahat,
    float* __restrict__ outPolicy, float* __restrict__ outEntropy,
    int* __restrict__ topk_idx, float* __restrict__ tanhs,
    float* __restrict__ G, float* __restrict__ A_ws) {
  int b = blockIdx.x, t = threadIdx.x;
  int wave = t >> 6, lane = t & 63;
  const float* s = scores + b*4096;

  __shared__ float redf[8];
  __shared__ int   redi[4];
  __shared__ unsigned int candK[256];
  __shared__ int   candI[256];
  __shared__ int   cnt;
  __shared__ int   idxl[64];
  __shared__ float Al[64*65];
  __shared__ float di[64];

  float v[16];
  unsigned int u[16];
  #pragma unroll
  for (int j = 0; j < 16; ++j) {
    float x = s[j*256 + t];
    v[j] = x;
    unsigned int sb = __float_as_uint(x);
    u[j] = (sb & 0x80000000u) ? ~sb : (sb | 0x80000000u);
  }

  // ---- softmax stats ----
  float mx = v[0];
  #pragma unroll
  for (int j = 1; j < 16; ++j) mx = fmaxf(mx, v[j]);
  #pragma unroll
  for (int off = 32; off; off >>= 1) mx = fmaxf(mx, __shfl_xor(mx, off));
  if (lane == 0) redf[wave] = mx;
  __syncthreads();
  mx = fmaxf(fmaxf(redf[0], redf[1]), fmaxf(redf[2], redf[3]));
  __syncthreads();
  float S = 0.f, E1 = 0.f;
  #pragma unroll
  for (int j = 0; j < 16; ++j) { float e = expf(v[j] - mx); S += e; E1 += e*(v[j]-mx); }
  #pragma unroll
  for (int off = 32; off; off >>= 1) { S += __shfl_xor(S, off); E1 += __shfl_xor(E1, off); }
  if (lane == 0) { redf[wave] = S; redf[4 + wave] = E1; }
  __syncthreads();
  S  = redf[0] + redf[1] + redf[2] + redf[3];
  E1 = redf[4] + redf[5] + redf[6] + redf[7];
  float logS = logf(S);
  if (t == 0) outEntropy[b] = logS - E1 / S;
  __syncthreads();

  // ---- binary search for T* = max T with count(key >= T) >= 64 ----
  unsigned long long lo = 0ull, hi = 0xFFFFFFFFull;
  for (int it = 0; it < 32; ++it) {
    unsigned long long mid = lo + ((hi - lo + 1ull) >> 1);
    unsigned int midu = (unsigned int)mid;
    int c = 0;
    #pragma unroll
    for (int j = 0; j < 16; ++j) c += (u[j] >= midu) ? 1 : 0;
    #pragma unroll
    for (int off = 32; off; off >>= 1) c += __shfl_xor(c, off);
    if (lane == 0) redi[wave] = c;
    __syncthreads();
    int tot = redi[0] + redi[1] + redi[2] + redi[3];
    __syncthreads();
    if (tot >= 64) lo = mid; else hi = mid - 1ull;
  }
  unsigned int Tstar = (unsigned int)lo;

  // ---- compact candidates (key >= T*), expected exactly 64 ----
  if (t == 0) cnt = 0;
  __syncthreads();
  #pragma unroll
  for (int j = 0; j < 16; ++j) {
    if (u[j] >= Tstar) {
      int p = atomicAdd(&cnt, 1);
      if (p < 256) { candK[p] = u[j]; candI[p] = j*256 + t; }
    }
  }
  __syncthreads();
  int nc = cnt < 256 ? cnt : 256;

  // ---- single-wave ordered extraction: 64 rounds, (val desc, idx asc) ----
  if (t < 64) {
    unsigned long long c0 = 0, c1 = 0, c2 = 0, c3 = 0;
    {
      int p;
      p = t;       if (p < nc) c0 = ((unsigned long long)candK[p] << 32) | (unsigned int)(~candI[p]);
      p = 64 + t;  if (p < nc) c1 = ((unsigned long long)candK[p] << 32) | (unsigned int)(~candI[p]);
      p = 128 + t; if (p < nc) c2 = ((unsigned long long)candK[p] << 32) | (unsigned int)(~candI[p]);
      p = 192 + t; if (p < nc) c3 = ((unsigned long long)candK[p] << 32) | (unsigned int)(~candI[p]);
    }
    float vsum = 0.f;
    for (int k = 0; k < 64; ++k) {
      unsigned long long w = c0;
      if (c1 > w) w = c1;
      if (c2 > w) w = c2;
      if (c3 > w) w = c3;
      #pragma unroll
      for (int off = 32; off; off >>= 1) {
        unsigned long long o = __shfl_xor(w, off);
        if (o > w) w = o;
      }
      unsigned int ku = (unsigned int)(w >> 32);
      int wi = (int)(~(unsigned int)(w & 0xFFFFFFFFull));
      if (t == 0) {
        unsigned int sb = (ku & 0x80000000u) ? (ku & 0x7FFFFFFFu) : ~ku;
        float val = __uint_as_float(sb);
        topk_idx[b*64 + k] = wi;
        idxl[k] = wi;
        tanhs[b*64 + k] = tanhf(val);
        vsum += val;
      }
      if (c0 == w) c0 = 0;
      if (c1 == w) c1 = 0;
      if (c2 == w) c2 = 0;
      if (c3 == w) c3 = 0;
    }
    if (t == 0) outPolicy[b] = vsum * (1.0f/64.0f) - mx - logS;
  }
  __syncthreads();

  // ---- gather G[b,k,:] = node_embs[b, idx[k], :] ----
  for (int e = t; e < 8192; e += 256) {
    int k = e >> 7, d = e & 127;
    G[(size_t)b*8192 + e] = node_embs[((size_t)(b*4096 + idxl[k]))*128 + d];
  }

  // ---- pooled adjacency + sym-normalize ----
  const float* Ab = Ahat + (size_t)b * 4096 * 4096;
  for (int e = t; e < 4096; e += 256) {
    int p = e >> 6, q = e & 63;
    Al[p*65 + q] = Ab[(size_t)idxl[p]*4096 + idxl[q]];
  }
  __syncthreads();
  if (t < 64) {
    float ssum = 0.f;
    for (int p = 0; p < 64; ++p) ssum += Al[p*65 + t];
    di[t] = 1.0f / sqrtf(ssum);
  }
  __syncthreads();
  for (int e = t; e < 4096; e += 256) {
    int p = e >> 6, q = e & 63;
    A_ws[(size_t)b*4096 + e] = di[p] * di[q] * Al[p*65 + q];
  }
}

// ---------- K3: update & reset gates ----------
__global__ __launch_bounds__(128) void k_gru1(const float* __restrict__ G,
    const float* __restrict__ tanhs, const float* __restrict__ prevQ,
    const float* __restrict__ Wu, const float* __restrict__ Uu, const float* __restrict__ bu,
    const float* __restrict__ Wr, const float* __restrict__ Ur, const float* __restrict__ br,
    float* __restrict__ u_out, float* __restrict__ r_out) {
  int b = blockIdx.x >> 5, i0 = (blockIdx.x & 31) * 4, k = threadIdx.x;
  __shared__ float Gl[64*129];
  __shared__ float Wl[4][128], Ul[4][128], Wrl[4][128], Url[4][128];
  for (int e = k; e < 8192; e += 128) { int rr = e >> 7; Gl[rr*129 + (e & 127)] = G[(size_t)b*8192 + e]; }
  #pragma unroll
  for (int ii = 0; ii < 4; ++ii) {
    Wl[ii][k]  = Wu[(i0+ii)*128 + k]; Ul[ii][k]  = Uu[(i0+ii)*128 + k];
    Wrl[ii][k] = Wr[(i0+ii)*128 + k]; Url[ii][k] = Ur[(i0+ii)*128 + k];
  }
  __syncthreads();
  int km = k & 63;
  float tk = tanhs[b*64 + km];
  const float* Gr = Gl + km*129;
  const float* Q = prevQ + (size_t)b*16384;
  float aW[4] = {0,0,0,0}, aU[4] = {0,0,0,0}, aWr[4] = {0,0,0,0}, aUr[4] = {0,0,0,0};
  for (int j = 0; j < 128; ++j) {
    float g = Gr[j], q = Q[j*128 + k];
    #pragma unroll
    for (int ii = 0; ii < 4; ++ii) {
      aW[ii]  += Wl[ii][j]  * g;  aU[ii]  += Ul[ii][j]  * q;
      aWr[ii] += Wrl[ii][j] * g;  aUr[ii] += Url[ii][j] * q;
    }
  }
  #pragma unroll
  for (int ii = 0; ii < 4; ++ii) {
    int i = i0 + ii; size_t o = ((size_t)b*128 + i)*128 + k;
    u_out[o] = sigmoidf_(aW[ii]*tk  + aU[ii]  + bu[i*128 + k]);
    r_out[o] = sigmoidf_(aWr[ii]*tk + aUr[ii] + br[i*128 + k]);
  }
}

// ---------- K4: h_cap + new_Q ----------
__global__ __launch_bounds__(128) void k_gru2(const float* __restrict__ G,
    const float* __restrict__ tanhs, const float* __restrict__ prevQ,
    const float* __restrict__ Wh, const float* __restrict__ Uh, const float* __restrict__ bh,
    const float* __restrict__ u_ws, const float* __restrict__ r_ws,
    float* __restrict__ Qn) {
  int b = blockIdx.x >> 5, i0 = (blockIdx.x & 31) * 4, k = threadIdx.x;
  __shared__ float Gl[64*129];
  __shared__ float Wl[4][128], Ul[4][128];
  for (int e = k; e < 8192; e += 128) { int rr = e >> 7; Gl[rr*129 + (e & 127)] = G[(size_t)b*8192 + e]; }
  #pragma unroll
  for (int ii = 0; ii < 4; ++ii) {
    Wl[ii][k] = Wh[(i0+ii)*128 + k]; Ul[ii][k] = Uh[(i0+ii)*128 + k];
  }
  __syncthreads();
  int km = k & 63;
  float tk = tanhs[b*64 + km];
  const float* Gr = Gl + km*129;
  const float* Q = prevQ + (size_t)b*16384;
  const float* Rw = r_ws + (size_t)b*16384;
  float aW[4] = {0,0,0,0}, aU[4] = {0,0,0,0};
  for (int j = 0; j < 128; ++j) {
    float g = Gr[j];
    float rq = Rw[j*128 + k] * Q[j*128 + k];
    #pragma unroll
    for (int ii = 0; ii < 4; ++ii) { aW[ii] += Wl[ii][j]*g; aU[ii] += Ul[ii][j]*rq; }
  }
  #pragma unroll
  for (int ii = 0; ii < 4; ++ii) {
    int i = i0 + ii; size_t o = ((size_t)b*128 + i)*128 + k;
    float hc = tanhf(aW[ii]*tk + aU[ii] + bh[i*128 + k]);
    float uu = u_ws[o];
    float qq = Q[i*128 + k];
    Qn[o] = (1.f - uu)*qq + uu*hc;
  }
}

// ---------- K5: H0 = G@Qn; h1 = relu(A@H0); M = h1@Ws; out = (h1 + relu(A@M))/2 ----------
__global__ __launch_bounds__(512) void k_final(const float* __restrict__ G,
    const float* __restrict__ A_ws, const float* __restrict__ Qn,
    const float* __restrict__ Ws, float* __restrict__ out) {
  int b = blockIdx.x, t = threadIdx.x;
  int pg = t >> 7, d = t & 127;
  __shared__ float Al[64*64];
  __shared__ float buf[64*128];
  const float* Gb = G  + (size_t)b*8192;
  const float* Q  = Qn + (size_t)b*16384;
  float* ob = out + (size_t)b*8192;
  for (int e = t; e < 4096; e += 512) Al[e] = A_ws[(size_t)b*4096 + e];
  __syncthreads();

  float acc[16];
  #pragma unroll
  for (int ii = 0; ii < 16; ++ii) acc[ii] = 0.f;
  for (int j = 0; j < 128; ++j) {
    float q = Q[j*128 + d];
    #pragma unroll
    for (int ii = 0; ii < 16; ++ii) acc[ii] += Gb[(pg + ii*4)*128 + j] * q;
  }
  #pragma unroll
  for (int ii = 0; ii < 16; ++ii) buf[(pg + ii*4)*128 + d] = acc[ii];
  __syncthreads();

  float hv[16];
  #pragma unroll
  for (int ii = 0; ii < 16; ++ii) acc[ii] = 0.f;
  for (int q2 = 0; q2 < 64; ++q2) {
    float h0 = buf[q2*128 + d];
    #pragma unroll
    for (int ii = 0; ii < 16; ++ii) acc[ii] += Al[(pg + ii*4)*64 + q2] * h0;
  }
  #pragma unroll
  for (int ii = 0; ii < 16; ++ii) { hv[ii] = fmaxf(acc[ii], 0.f); ob[(pg + ii*4)*128 + d] = hv[ii]; }
  __syncthreads();

  #pragma unroll
  for (int ii = 0; ii < 16; ++ii) acc[ii] = 0.f;
  for (int j = 0; j < 128; ++j) {
    float w = Ws[j*128 + d];
    #pragma unroll
    for (int ii = 0; ii < 16; ++ii) acc[ii] += ob[(pg + ii*4)*128 + j] * w;
  }
  #pragma unroll
  for (int ii = 0; ii < 16; ++ii) buf[(pg + ii*4)*128 + d] = acc[ii];
  __syncthreads();

  #pragma unroll
  for (int ii = 0; ii < 16; ++ii) acc[ii] = 0.f;
  for (int q2 = 0; q2 < 64; ++q2) {
    float mv = buf[q2*128 + d];
    #pragma unroll
    for (int ii = 0; ii < 16; ++ii) acc[ii] += Al[(pg + ii*4)*64 + q2] * mv;
  }
  #pragma unroll
  for (int ii = 0; ii < 16; ++ii)
    ob[(pg + ii*4)*128 + d] = 0.5f * (hv[ii] + fmaxf(acc[ii], 0.f));
}

extern "C" void kernel_launch(void* const* d_in, const int* in_sizes, int n_in,
                              void* d_out, int out_size, void* d_ws, size_t ws_size,
                              hipStream_t stream) {
  const float* Ahat      = (const float*)d_in[0];
  const float* node_embs = (const float*)d_in[1];
  const float* ht        = (const float*)d_in[3];
  const float* prev_Q    = (const float*)d_in[4];
  const float* W_map     = (const float*)d_in[5];
  const float* b_map     = (const float*)d_in[6];
  const float* Wu = (const float*)d_in[7];
  const float* Uu = (const float*)d_in[8];
  const float* bu = (const float*)d_in[9];
  const float* Wr = (const float*)d_in[10];
  const float* Ur = (const float*)d_in[11];
  const float* br = (const float*)d_in[12];
  const float* Wh = (const float*)d_in[13];
  const float* Uh = (const float*)d_in[14];
  const float* bh = (const float*)d_in[15];
  const float* staticW = (const float*)d_in[16];

  float* out = (float*)d_out;
  float* ws  = (float*)d_ws;
  float* scores    = ws;                 // 32768
  int*   topk_idx  = (int*)(ws + 32768); // 512
  float* tanhs     = ws + 33280;         // 512
  float* G         = ws + 33792;         // 65536
  float* u_ws      = ws + 99328;         // 131072
  float* r_ws      = ws + 230400;        // 131072
  float* Qn        = ws + 361472;        // 131072
  float* A_ws      = ws + 492544;        // 32768

  float* policy  = out + 65536;
  float* scr_out = out + 65544;
  float* entropy = out + 66568;

  k_scores<<<128, 256, 0, stream>>>(node_embs, ht, W_map, b_map, scores, scr_out);
  k_select<<<8, 256, 0, stream>>>(scores, node_embs, Ahat, policy, entropy,
                                  topk_idx, tanhs, G, A_ws);
  k_gru1  <<<256, 128, 0, stream>>>(G, tanhs, prev_Q, Wu, Uu, bu, Wr, Ur, br, u_ws, r_ws);
  k_gru2  <<<256, 128, 0, stream>>>(G, tanhs, prev_Q, Wh, Uh, bh, u_ws, r_ws, Qn);
  k_final <<<8, 512, 0, stream>>>(G, A_ws, Qn, staticW, out);
}